// Round 1
// baseline (875.824 us; speedup 1.0000x reference)
//
#include <hip/hip_runtime.h>
#include <hip/hip_bf16.h>

#define NUM_EXPERTS 32
#define HIDDEN 2048
#define INTER 768
#define TOPK 4
#define T_TOKENS 1024
#define CAP 1024

#define MT 192      // token slots per expert tile (count ~124 +- 10; one pass)
#define BK 32       // K step
#define PAD 40      // LDS row stride in bf16 (16B-aligned, 2-way bank alias = free)

typedef __bf16 bf16x8 __attribute__((ext_vector_type(8)));
typedef float floatx4 __attribute__((ext_vector_type(4)));

// ---------------------------------------------------------------- routing ---
__global__ void route_kernel(const int* __restrict__ ri, int* __restrict__ counts,
                             int* __restrict__ tok_list) {
    int t = blockIdx.x * blockDim.x + threadIdx.x;
    if (t >= T_TOKENS) return;
    int idx[TOPK];
#pragma unroll
    for (int j = 0; j < TOPK; ++j) idx[j] = ri[t * TOPK + j];
#pragma unroll
    for (int j = 0; j < TOPK; ++j) {
        int e = idx[j];
        bool dup = false;
#pragma unroll
        for (int l = 0; l < TOPK; ++l)
            if (l < j && idx[l] == e) dup = true;
        if (!dup) {
            int s = atomicAdd(&counts[e], 1);
            tok_list[e * CAP + s] = t;
        }
    }
}

// ------------------------------------------------------- gemm1: x @ Wgu -----
// block: 256 thr (4 waves, waves split M: 48 rows each).
// N per block: 64 act cols -> stages 64 gate cols + matching 64 up cols (128 MFMA-N).
__global__ __launch_bounds__(256) void gemm1_kernel(
    const float* __restrict__ x, const float* __restrict__ rw,
    const float* __restrict__ Wgu, const int* __restrict__ counts,
    const int* __restrict__ tok_list, __bf16* __restrict__ act) {
    const int e = blockIdx.y;
    const int n0 = blockIdx.x * 64;
    const int count = counts[e];
    if (count == 0) return;
    const int tid = threadIdx.x;
    const int wave = tid >> 6;
    const int lane = tid & 63;
    const int fr = lane & 15;   // frag row / col
    const int fq = lane >> 4;   // frag quad

    __shared__ int s_off;
    __shared__ int s_tok[MT];
    __shared__ float s_w[MT];
    __shared__ __align__(16) __bf16 As[MT * PAD];
    __shared__ __align__(16) __bf16 Bs[128 * PAD];

    if (tid == 0) {
        int o = 0;
        for (int i = 0; i < e; ++i) o += counts[i];
        s_off = o;
    }

    const size_t wbase = (size_t)e * HIDDEN * (2 * INTER);

    for (int m0 = 0; m0 < count; m0 += MT) {
        for (int r = tid; r < MT; r += 256) {
            int slot = m0 + r;
            int t = (slot < count) ? tok_list[e * CAP + slot] : 0;
            s_tok[r] = t;
            s_w[r] = (slot < count) ? rw[t * NUM_EXPERTS + e] : 0.f;
        }
        __syncthreads();

        floatx4 acc[3][8];
#pragma unroll
        for (int ms = 0; ms < 3; ++ms)
#pragma unroll
            for (int ns = 0; ns < 8; ++ns)
                acc[ms][ns] = (floatx4){0.f, 0.f, 0.f, 0.f};

        for (int k0 = 0; k0 < HIDDEN; k0 += BK) {
            // stage A: MT x 32 f32 (gathered token rows) -> bf16 LDS
            for (int idx = tid; idx < MT * 2; idx += 256) {
                int r = idx >> 1;
                int h = (idx & 1) * 16;
                const float* src = x + (size_t)s_tok[r] * HIDDEN + k0 + h;
                float4 f0 = ((const float4*)src)[0];
                float4 f1 = ((const float4*)src)[1];
                float4 f2 = ((const float4*)src)[2];
                float4 f3 = ((const float4*)src)[3];
                bf16x8 p0, p1;
                p0[0] = (__bf16)f0.x; p0[1] = (__bf16)f0.y; p0[2] = (__bf16)f0.z; p0[3] = (__bf16)f0.w;
                p0[4] = (__bf16)f1.x; p0[5] = (__bf16)f1.y; p0[6] = (__bf16)f1.z; p0[7] = (__bf16)f1.w;
                p1[0] = (__bf16)f2.x; p1[1] = (__bf16)f2.y; p1[2] = (__bf16)f2.z; p1[3] = (__bf16)f2.w;
                p1[4] = (__bf16)f3.x; p1[5] = (__bf16)f3.y; p1[6] = (__bf16)f3.z; p1[7] = (__bf16)f3.w;
                *(bf16x8*)&As[r * PAD + h] = p0;
                *(bf16x8*)&As[r * PAD + h + 8] = p1;
            }
            // stage B: 32k x 128n (n<64: gate col n0+n; n>=64: up col INTER+n0+n-64)
            // LDS layout transposed: Bs[n][k]
            for (int idx = tid; idx < 512; idx += 256) {
                int n = idx & 127;
                int kh = idx >> 7;
                int g = (n < 64) ? (n0 + n) : (INTER + n0 + (n - 64));
                const float* src = Wgu + wbase + (size_t)(k0 + kh * 8) * (2 * INTER) + g;
                bf16x8 p;
#pragma unroll
                for (int j = 0; j < 8; ++j) p[j] = (__bf16)src[(size_t)j * (2 * INTER)];
                *(bf16x8*)&Bs[n * PAD + kh * 8] = p;
            }
            __syncthreads();

            bf16x8 af[3], bfr[8];
#pragma unroll
            for (int ms = 0; ms < 3; ++ms)
                af[ms] = *(const bf16x8*)&As[(wave * 48 + ms * 16 + fr) * PAD + fq * 8];
#pragma unroll
            for (int ns = 0; ns < 8; ++ns)
                bfr[ns] = *(const bf16x8*)&Bs[(ns * 16 + fr) * PAD + fq * 8];
#pragma unroll
            for (int ms = 0; ms < 3; ++ms)
#pragma unroll
                for (int ns = 0; ns < 8; ++ns)
                    acc[ms][ns] = __builtin_amdgcn_mfma_f32_16x16x32_bf16(af[ms], bfr[ns], acc[ms][ns], 0, 0, 0);
            __syncthreads();
        }

        // epilogue: act = silu(gate) * up * rw, store bf16 compact
        const int off = s_off;
#pragma unroll
        for (int ms = 0; ms < 3; ++ms) {
            int rbase = wave * 48 + ms * 16 + fq * 4;
#pragma unroll
            for (int i = 0; i < 4; ++i) {
                int slot = m0 + rbase + i;
                if (slot < count) {
                    float w = s_w[rbase + i];
#pragma unroll
                    for (int ns = 0; ns < 4; ++ns) {
                        float gv = acc[ms][ns][i];
                        float uv = acc[ms][ns + 4][i];
                        float a = gv / (1.f + __expf(-gv)) * uv * w;
                        act[(size_t)(off + slot) * INTER + n0 + ns * 16 + fr] = (__bf16)a;
                    }
                }
            }
        }
        __syncthreads();
    }
}

// ------------------------------------------------- gemm2: act @ Wd -> out ---
__global__ __launch_bounds__(256) void gemm2_kernel(
    const __bf16* __restrict__ act, const float* __restrict__ Wd,
    const int* __restrict__ counts, const int* __restrict__ tok_list,
    float* __restrict__ out) {
    const int e = blockIdx.y;
    const int n0 = blockIdx.x * 128;
    const int count = counts[e];
    if (count == 0) return;
    const int tid = threadIdx.x;
    const int wave = tid >> 6;
    const int lane = tid & 63;
    const int fr = lane & 15;
    const int fq = lane >> 4;

    __shared__ int s_off;
    __shared__ int s_tok[MT];
    __shared__ __align__(16) __bf16 As[MT * PAD];
    __shared__ __align__(16) __bf16 Bs[128 * PAD];

    if (tid == 0) {
        int o = 0;
        for (int i = 0; i < e; ++i) o += counts[i];
        s_off = o;
    }

    const size_t wbase = (size_t)e * INTER * HIDDEN;

    for (int m0 = 0; m0 < count; m0 += MT) {
        for (int r = tid; r < MT; r += 256) {
            int slot = m0 + r;
            s_tok[r] = (slot < count) ? tok_list[e * CAP + slot] : 0;
        }
        __syncthreads();

        floatx4 acc[3][8];
#pragma unroll
        for (int ms = 0; ms < 3; ++ms)
#pragma unroll
            for (int ns = 0; ns < 8; ++ns)
                acc[ms][ns] = (floatx4){0.f, 0.f, 0.f, 0.f};

        for (int k0 = 0; k0 < INTER; k0 += BK) {
            // stage A: act rows already bf16, direct 16B copies
            for (int r = tid; r < MT; r += 256) {
                int slot = min(m0 + r, count - 1);
                const __bf16* src = act + (size_t)(s_off + slot) * INTER + k0;
#pragma unroll
                for (int u = 0; u < 4; ++u)
                    *(bf16x8*)&As[r * PAD + u * 8] = ((const bf16x8*)src)[u];
            }
            // stage B: 32k x 128n from Wd, transposed into Bs[n][k]
            for (int idx = tid; idx < 512; idx += 256) {
                int n = idx & 127;
                int kh = idx >> 7;
                const float* src = Wd + wbase + (size_t)(k0 + kh * 8) * HIDDEN + n0 + n;
                bf16x8 p;
#pragma unroll
                for (int j = 0; j < 8; ++j) p[j] = (__bf16)src[(size_t)j * HIDDEN];
                *(bf16x8*)&Bs[n * PAD + kh * 8] = p;
            }
            __syncthreads();

            bf16x8 af[3], bfr[8];
#pragma unroll
            for (int ms = 0; ms < 3; ++ms)
                af[ms] = *(const bf16x8*)&As[(wave * 48 + ms * 16 + fr) * PAD + fq * 8];
#pragma unroll
            for (int ns = 0; ns < 8; ++ns)
                bfr[ns] = *(const bf16x8*)&Bs[(ns * 16 + fr) * PAD + fq * 8];
#pragma unroll
            for (int ms = 0; ms < 3; ++ms)
#pragma unroll
                for (int ns = 0; ns < 8; ++ns)
                    acc[ms][ns] = __builtin_amdgcn_mfma_f32_16x16x32_bf16(af[ms], bfr[ns], acc[ms][ns], 0, 0, 0);
            __syncthreads();
        }

        // epilogue: scatter-accumulate into out rows (uncontended f32 atomics)
#pragma unroll
        for (int ms = 0; ms < 3; ++ms) {
            int rbase = wave * 48 + ms * 16 + fq * 4;
#pragma unroll
            for (int i = 0; i < 4; ++i) {
                int slot = m0 + rbase + i;
                if (slot < count) {
                    int t = s_tok[rbase + i];
#pragma unroll
                    for (int ns = 0; ns < 8; ++ns)
                        atomicAdd(&out[(size_t)t * HIDDEN + n0 + ns * 16 + fr], acc[ms][ns][i]);
                }
            }
        }
        __syncthreads();
    }
}

// ---------------------------------------------------------------- launch ----
extern "C" void kernel_launch(void* const* d_in, const int* in_sizes, int n_in,
                              void* d_out, int out_size, void* d_ws, size_t ws_size,
                              hipStream_t stream) {
    const float* x   = (const float*)d_in[0];
    const float* rw  = (const float*)d_in[1];
    const float* Wgu = (const float*)d_in[2];
    const float* Wd  = (const float*)d_in[3];
    const int*   ri  = (const int*)d_in[4];
    float* out = (float*)d_out;

    int* counts   = (int*)d_ws;                                  // 32 ints
    int* tok_list = (int*)((char*)d_ws + 512);                   // 32*1024 ints
    __bf16* act   = (__bf16*)((char*)d_ws + 512 + NUM_EXPERTS * CAP * 4);  // <=4096*768 bf16

    hipMemsetAsync(d_ws, 0, 512, stream);
    hipMemsetAsync(d_out, 0, (size_t)T_TOKENS * HIDDEN * sizeof(float), stream);

    route_kernel<<<dim3(T_TOKENS / 256), 256, 0, stream>>>(ri, counts, tok_list);
    gemm1_kernel<<<dim3(INTER / 64, NUM_EXPERTS), 256, 0, stream>>>(x, rw, Wgu, counts, tok_list, act);
    gemm2_kernel<<<dim3(HIDDEN / 128, NUM_EXPERTS), 256, 0, stream>>>(act, Wd, counts, tok_list, out);
}

// Round 2
// 789.755 us; speedup vs baseline: 1.1090x; 1.1090x over previous
//
#include <hip/hip_runtime.h>
#include <hip/hip_bf16.h>

#define NUM_EXPERTS 32
#define HIDDEN 2048
#define INTER 768
#define TOPK 4
#define T_TOKENS 1024
#define CAP 1024

#define MT 64       // token slots per block (z-split x3, stride-192 safety loop)
#define BK 64       // K step
#define LSTR 72     // LDS row stride in bf16 elements (16B-multiple)

typedef __bf16 bf16x8 __attribute__((ext_vector_type(8)));
typedef float floatx4 __attribute__((ext_vector_type(4)));

// XOR-swizzled LDS element offset: row-major stride LSTR, 8-elem (16B) k-blocks
// swizzled by row>>2 to break the n=4*lane staging-write bank pattern.
__device__ __forceinline__ int swz(int row, int kq) {
    return row * LSTR + (((kq ^ (row >> 2)) & 7) << 3);
}

// ---------------------------------------------------------------- routing ---
__global__ void route_kernel(const int* __restrict__ ri, int* __restrict__ counts,
                             int* __restrict__ tok_list) {
    int t = blockIdx.x * blockDim.x + threadIdx.x;
    if (t >= T_TOKENS) return;
    int idx[TOPK];
#pragma unroll
    for (int j = 0; j < TOPK; ++j) idx[j] = ri[t * TOPK + j];
#pragma unroll
    for (int j = 0; j < TOPK; ++j) {
        int e = idx[j];
        bool dup = false;
#pragma unroll
        for (int l = 0; l < TOPK; ++l)
            if (l < j && idx[l] == e) dup = true;
        if (!dup) {
            int s = atomicAdd(&counts[e], 1);
            tok_list[e * CAP + s] = t;
        }
    }
}

// ------------------------------------------------------- gemm1: x @ Wgu -----
// grid (INTER/64, E, 3). block 256 = 4 waves in 2x2 (M x N) arrangement.
// Per block: M=64 token slots, N=64 act cols (gate+up interleaved -> 128 MFMA-N).
__global__ __launch_bounds__(256) void gemm1_kernel(
    const float* __restrict__ x, const float* __restrict__ rw,
    const float* __restrict__ Wgu, const int* __restrict__ counts,
    const int* __restrict__ tok_list, __bf16* __restrict__ act) {
    const int e = blockIdx.y;
    const int n0 = blockIdx.x * 64;
    const int count = counts[e];
    const int tid = threadIdx.x;
    const int wave = tid >> 6;
    const int lane = tid & 63;
    const int fr = lane & 15;
    const int fq = lane >> 4;
    const int wr = wave >> 1;   // wave M-half
    const int wc = wave & 1;    // wave N-half

    __shared__ int s_off;
    __shared__ int s_tok[MT];
    __shared__ float s_w[MT];
    __shared__ __align__(16) __bf16 As[MT * LSTR];
    __shared__ __align__(16) __bf16 Bs[128 * LSTR];

    if (tid == 0) {
        int o = 0;
        for (int i = 0; i < e; ++i) o += counts[i];
        s_off = o;
    }

    const size_t wbase = (size_t)e * HIDDEN * (2 * INTER);

    // B staging geometry (constant across k0): thread owns 4 adjacent n, 8 k rows
    const int ng = (tid & 31) * 4;          // Bs row base (0..124)
    const int kg = tid >> 5;                // 8-k group (0..7)
    const int bwc = ng >> 6;
    const int bj = ng & 63;
    const int memcol = (bj < 32) ? (n0 + bwc * 32 + bj)
                                 : (INTER + n0 + bwc * 32 + (bj - 32));
    // A staging geometry
    const int ar = tid >> 2;                // row 0..63
    const int aq = tid & 3;                 // 16-k quarter

    for (int m0 = blockIdx.z * MT; m0 < count; m0 += 3 * MT) {
        __syncthreads();
        if (tid < MT) {
            int slot = m0 + tid;
            int t = (slot < count) ? tok_list[e * CAP + slot] : tok_list[e * CAP];
            s_tok[tid] = t;
            s_w[tid] = (slot < count) ? rw[t * NUM_EXPERTS + e] : 0.f;
        }
        __syncthreads();

        floatx4 acc[2][4];
#pragma unroll
        for (int ms = 0; ms < 2; ++ms)
#pragma unroll
            for (int nf = 0; nf < 4; ++nf)
                acc[ms][nf] = (floatx4){0.f, 0.f, 0.f, 0.f};

        for (int k0 = 0; k0 < HIDDEN; k0 += BK) {
            // ---- stage A: 64 rows x 64 k, f32 -> bf16
            {
                const float* src = x + (size_t)s_tok[ar] * HIDDEN + k0 + aq * 16;
                float4 f0 = ((const float4*)src)[0];
                float4 f1 = ((const float4*)src)[1];
                float4 f2 = ((const float4*)src)[2];
                float4 f3 = ((const float4*)src)[3];
                bf16x8 p0, p1;
                p0[0] = (__bf16)f0.x; p0[1] = (__bf16)f0.y; p0[2] = (__bf16)f0.z; p0[3] = (__bf16)f0.w;
                p0[4] = (__bf16)f1.x; p0[5] = (__bf16)f1.y; p0[6] = (__bf16)f1.z; p0[7] = (__bf16)f1.w;
                p1[0] = (__bf16)f2.x; p1[1] = (__bf16)f2.y; p1[2] = (__bf16)f2.z; p1[3] = (__bf16)f2.w;
                p1[4] = (__bf16)f3.x; p1[5] = (__bf16)f3.y; p1[6] = (__bf16)f3.z; p1[7] = (__bf16)f3.w;
                *(bf16x8*)&As[swz(ar, 2 * aq)] = p0;
                *(bf16x8*)&As[swz(ar, 2 * aq + 1)] = p1;
            }
            // ---- stage B: 64 k x 128 n, float4 loads + register transpose
            {
                const float* src = Wgu + wbase + (size_t)(k0 + kg * 8) * (2 * INTER) + memcol;
                float4 b[8];
#pragma unroll
                for (int r8 = 0; r8 < 8; ++r8)
                    b[r8] = *(const float4*)(src + (size_t)r8 * (2 * INTER));
#pragma unroll
                for (int c = 0; c < 4; ++c) {
                    bf16x8 p;
#pragma unroll
                    for (int r8 = 0; r8 < 8; ++r8)
                        p[r8] = (__bf16)((const float*)&b[r8])[c];
                    *(bf16x8*)&Bs[swz(ng + c, kg)] = p;
                }
            }
            __syncthreads();

#pragma unroll
            for (int ks = 0; ks < 2; ++ks) {
                bf16x8 af[2], bf[4];
#pragma unroll
                for (int ms = 0; ms < 2; ++ms)
                    af[ms] = *(const bf16x8*)&As[swz(wr * 32 + ms * 16 + fr, ks * 4 + fq)];
#pragma unroll
                for (int nf = 0; nf < 4; ++nf)
                    bf[nf] = *(const bf16x8*)&Bs[swz(wc * 64 + nf * 16 + fr, ks * 4 + fq)];
#pragma unroll
                for (int ms = 0; ms < 2; ++ms)
#pragma unroll
                    for (int nf = 0; nf < 4; ++nf)
                        acc[ms][nf] = __builtin_amdgcn_mfma_f32_16x16x32_bf16(af[ms], bf[nf], acc[ms][nf], 0, 0, 0);
            }
            __syncthreads();
        }

        // epilogue: silu(gate)*up*rw -> act bf16 (frags nf<2 gate, nf>=2 up)
        const int off = s_off;
#pragma unroll
        for (int ms = 0; ms < 2; ++ms) {
            int rbase = wr * 32 + ms * 16 + fq * 4;
#pragma unroll
            for (int i = 0; i < 4; ++i) {
                int slot = m0 + rbase + i;
                if (slot < count) {
                    float w = s_w[rbase + i];
#pragma unroll
                    for (int nf = 0; nf < 2; ++nf) {
                        float gv = acc[ms][nf][i];
                        float uv = acc[ms][nf + 2][i];
                        float a = gv / (1.f + __expf(-gv)) * uv * w;
                        act[(size_t)(off + slot) * INTER + n0 + wc * 32 + nf * 16 + fr] = (__bf16)a;
                    }
                }
            }
        }
    }
}

// ------------------------------------------------- gemm2: act @ Wd -> out ---
// grid (HIDDEN/128, E, 3). Same block structure; N=128 out cols.
__global__ __launch_bounds__(256) void gemm2_kernel(
    const __bf16* __restrict__ act, const float* __restrict__ Wd,
    const int* __restrict__ counts, const int* __restrict__ tok_list,
    float* __restrict__ out) {
    const int e = blockIdx.y;
    const int n0 = blockIdx.x * 128;
    const int count = counts[e];
    const int tid = threadIdx.x;
    const int wave = tid >> 6;
    const int lane = tid & 63;
    const int fr = lane & 15;
    const int fq = lane >> 4;
    const int wr = wave >> 1;
    const int wc = wave & 1;

    __shared__ int s_off;
    __shared__ int s_tok[MT];
    __shared__ __align__(16) __bf16 As[MT * LSTR];
    __shared__ __align__(16) __bf16 Bs[128 * LSTR];

    if (tid == 0) {
        int o = 0;
        for (int i = 0; i < e; ++i) o += counts[i];
        s_off = o;
    }

    const size_t wbase = (size_t)e * INTER * HIDDEN;
    const int ng = (tid & 31) * 4;
    const int kg = tid >> 5;
    const int ar = tid >> 2;
    const int aq = tid & 3;

    for (int m0 = blockIdx.z * MT; m0 < count; m0 += 3 * MT) {
        __syncthreads();
        if (tid < MT) {
            int slot = m0 + tid;
            s_tok[tid] = (slot < count) ? tok_list[e * CAP + slot] : 0;
        }
        __syncthreads();

        floatx4 acc[2][4];
#pragma unroll
        for (int ms = 0; ms < 2; ++ms)
#pragma unroll
            for (int nf = 0; nf < 4; ++nf)
                acc[ms][nf] = (floatx4){0.f, 0.f, 0.f, 0.f};

        for (int k0 = 0; k0 < INTER; k0 += BK) {
            // ---- stage A: act rows already bf16
            {
                int slot = min(m0 + ar, count - 1);
                const __bf16* src = act + (size_t)(s_off + slot) * INTER + k0 + aq * 16;
                bf16x8 p0 = ((const bf16x8*)src)[0];
                bf16x8 p1 = ((const bf16x8*)src)[1];
                *(bf16x8*)&As[swz(ar, 2 * aq)] = p0;
                *(bf16x8*)&As[swz(ar, 2 * aq + 1)] = p1;
            }
            // ---- stage B: 64 k x 128 n from Wd
            {
                const float* src = Wd + wbase + (size_t)(k0 + kg * 8) * HIDDEN + n0 + ng;
                float4 b[8];
#pragma unroll
                for (int r8 = 0; r8 < 8; ++r8)
                    b[r8] = *(const float4*)(src + (size_t)r8 * HIDDEN);
#pragma unroll
                for (int c = 0; c < 4; ++c) {
                    bf16x8 p;
#pragma unroll
                    for (int r8 = 0; r8 < 8; ++r8)
                        p[r8] = (__bf16)((const float*)&b[r8])[c];
                    *(bf16x8*)&Bs[swz(ng + c, kg)] = p;
                }
            }
            __syncthreads();

#pragma unroll
            for (int ks = 0; ks < 2; ++ks) {
                bf16x8 af[2], bf[4];
#pragma unroll
                for (int ms = 0; ms < 2; ++ms)
                    af[ms] = *(const bf16x8*)&As[swz(wr * 32 + ms * 16 + fr, ks * 4 + fq)];
#pragma unroll
                for (int nf = 0; nf < 4; ++nf)
                    bf[nf] = *(const bf16x8*)&Bs[swz(wc * 64 + nf * 16 + fr, ks * 4 + fq)];
#pragma unroll
                for (int ms = 0; ms < 2; ++ms)
#pragma unroll
                    for (int nf = 0; nf < 4; ++nf)
                        acc[ms][nf] = __builtin_amdgcn_mfma_f32_16x16x32_bf16(af[ms], bf[nf], acc[ms][nf], 0, 0, 0);
            }
            __syncthreads();
        }

        // epilogue: scatter-accumulate f32 atomics
#pragma unroll
        for (int ms = 0; ms < 2; ++ms) {
            int rbase = wr * 32 + ms * 16 + fq * 4;
#pragma unroll
            for (int i = 0; i < 4; ++i) {
                int slot = m0 + rbase + i;
                if (slot < count) {
                    int t = s_tok[rbase + i];
#pragma unroll
                    for (int nf = 0; nf < 4; ++nf)
                        atomicAdd(&out[(size_t)t * HIDDEN + n0 + wc * 64 + nf * 16 + fr], acc[ms][nf][i]);
                }
            }
        }
    }
}

// ---------------------------------------------------------------- launch ----
extern "C" void kernel_launch(void* const* d_in, const int* in_sizes, int n_in,
                              void* d_out, int out_size, void* d_ws, size_t ws_size,
                              hipStream_t stream) {
    const float* x   = (const float*)d_in[0];
    const float* rw  = (const float*)d_in[1];
    const float* Wgu = (const float*)d_in[2];
    const float* Wd  = (const float*)d_in[3];
    const int*   ri  = (const int*)d_in[4];
    float* out = (float*)d_out;

    int* counts   = (int*)d_ws;
    int* tok_list = (int*)((char*)d_ws + 512);
    __bf16* act   = (__bf16*)((char*)d_ws + 512 + NUM_EXPERTS * CAP * 4);

    hipMemsetAsync(d_ws, 0, 512, stream);
    hipMemsetAsync(d_out, 0, (size_t)T_TOKENS * HIDDEN * sizeof(float), stream);

    route_kernel<<<dim3(T_TOKENS / 256), 256, 0, stream>>>(ri, counts, tok_list);
    gemm1_kernel<<<dim3(INTER / 64, NUM_EXPERTS, 3), 256, 0, stream>>>(x, rw, Wgu, counts, tok_list, act);
    gemm2_kernel<<<dim3(HIDDEN / 128, NUM_EXPERTS, 3), 256, 0, stream>>>(act, Wd, counts, tok_list, out);
}